// Round 21
// baseline (421.229 us; speedup 1.0000x reference)
//
#include <hip/hip_runtime.h>
#include <hip/hip_bf16.h>

// Relative-position causal attention, B=4 H=16 Q=K=1024 D=64 (fp32 in/out).
// d_out = [output (BH*Q*D) | p_attn (BH*Q*K)] fp32.
// K1 k_scores: content scores (LDS-staged GEMM, counted vmcnt, 1-D grid).
// K2 k_rel_pv: rel+exp -> e to P + fused PR; 2x-unrolled software pipeline:
//              pc+bv prefetched ONE TILE AHEAD into named E/O register sets
//              (no runtime selects -> no scratch), stage 2 ahead, WAITVN(28).
// K3 k_pv: Pn = e*recip in place (final p_attn), out += Pn@V (1-D grid).

#define BH 64
#define SQ 1024
#define SK 1024
#define DH 64
#define SCALE 0.125f

typedef __attribute__((ext_vector_type(4))) float f32x4;
typedef __attribute__((ext_vector_type(8))) unsigned short ushort8;
typedef __attribute__((ext_vector_type(8))) __bf16 bf16x8;

static __device__ inline unsigned short f2bf(float x) {
    unsigned u = __float_as_uint(x);
    unsigned r = u + 0x7FFFu + ((u >> 16) & 1u);
    return (unsigned short)(r >> 16);
}
static __device__ inline float bf2f(unsigned short s) {
    return __uint_as_float(((unsigned)s) << 16);
}

struct Frag2 { bf16x8 h, l; };

// Load 8 fp32, scale, split into hi/lo bf16 fragments (hi+lo == scaled value).
static __device__ inline Frag2 load_split(const float* __restrict__ p, float scale) {
    float4 x0 = *reinterpret_cast<const float4*>(p);
    float4 x1 = *reinterpret_cast<const float4*>(p + 4);
    float v[8] = {x0.x, x0.y, x0.z, x0.w, x1.x, x1.y, x1.z, x1.w};
    ushort8 uh, ul;
#pragma unroll
    for (int j = 0; j < 8; ++j) {
        float s = v[j] * scale;
        unsigned short h = f2bf(s);
        float r = s - bf2f(h);
        uh[j] = h;
        ul[j] = f2bf(r);
    }
    Frag2 f;
    f.h = __builtin_bit_cast(bf16x8, uh);
    f.l = __builtin_bit_cast(bf16x8, ul);
    return f;
}

static __device__ inline bf16x8 pack_bf8(float4 x0, float4 x1) {
    float v[8] = {x0.x, x0.y, x0.z, x0.w, x1.x, x1.y, x1.z, x1.w};
    ushort8 u;
#pragma unroll
    for (int j = 0; j < 8; ++j) u[j] = f2bf(v[j]);
    return __builtin_bit_cast(bf16x8, u);
}

static __device__ inline bf16x8 load_bf8(const float* __restrict__ p) {
    float4 x0 = *reinterpret_cast<const float4*>(p);
    float4 x1 = *reinterpret_cast<const float4*>(p + 4);
    return pack_bf8(x0, x1);
}

static __device__ inline bf16x8 load_bf8_strided(const float* __restrict__ p, int stride) {
    ushort8 u;
#pragma unroll
    for (int j = 0; j < 8; ++j) u[j] = f2bf(p[(size_t)j * stride]);
    return __builtin_bit_cast(bf16x8, u);
}

#define MFMA(a, b, c) __builtin_amdgcn_mfma_f32_16x16x32_bf16((a), (b), (c), 0, 0, 0)

// async global -> LDS, 16B per lane; lds dest is wave-uniform base + lane*16
#define GLLD(g, s)                                                              \
    __builtin_amdgcn_global_load_lds(                                           \
        (const __attribute__((address_space(1))) void*)(g),                     \
        (__attribute__((address_space(3))) void*)(s), 16, 0, 0)

// stage a 64x64 fp32 tile (rows at src0 + row*DH) into buf[b]; WAVE-PRIVATE:
// wave w stages rows [w*16, w*16+16) and later reads only those rows.
// source pre-swizzled (chunk ^= row&7) so linear LDS + swizzled reads match.
#define STAGE64(src0, b)                                                        \
    do {                                                                        \
        _Pragma("unroll")                                                       \
        for (int j_ = 0; j_ < 4; ++j_) {                                        \
            const int idx_ = w * 256 + j_ * 64 + l;                             \
            const int row_ = idx_ >> 4;                                         \
            const int g_ = (idx_ & 15) ^ (row_ & 7);                            \
            GLLD((src0) + (size_t)row_ * DH + g_ * 4,                           \
                 &buf[b][w * 256 + j_ * 64]);                                   \
        }                                                                       \
    } while (0)

#define WAITVN(n)                                                               \
    do {                                                                        \
        asm volatile("s_waitcnt vmcnt(" #n ")" ::: "memory");                   \
        __builtin_amdgcn_sched_barrier(0);                                      \
    } while (0)

// ---------------- K1: content scores Q@K^T * scale -> P (zeros above diag).
// 1-D grid: qt = bid>>6 (high bits), bh = bid&63 -> resident sets span sizes.
__global__ __launch_bounds__(256, 4) void k_scores(const float* __restrict__ qp,
                                                   const float* __restrict__ kp,
                                                   float* __restrict__ P) {
    __shared__ float4 buf[2][1024];
    const int bid = blockIdx.x;
    const int qt = bid >> 6;
    const int bh = bid & 63;
    const int tid = threadIdx.x;
    const int w = tid >> 6, l = tid & 63;
    const int lm = l & 15, lg = l >> 4;
    const int q0 = qt * 64;

    Frag2 qh0[4], qh1[4];  // pre-scaled by SCALE
#pragma unroll
    for (int nt = 0; nt < 4; ++nt) {
        const float* qrow = qp + ((size_t)bh * SQ + q0 + nt * 16 + lm) * DH + lg * 8;
        qh0[nt] = load_split(qrow, SCALE);
        qh1[nt] = load_split(qrow + 32, SCALE);
    }
    const float* kb = kp + (size_t)bh * SK * DH;
    const int nt_ = qt + 1;

    STAGE64(kb, 0);
#pragma unroll 1
    for (int t = 0; t < nt_; ++t) {
        if (t + 1 < nt_) {
            STAGE64(kb + (size_t)(t + 1) * 64 * DH, (t + 1) & 1);
            WAITVN(4);  // stage(t)+stores(t-1) landed; stage(t+1) in flight
        } else {
            WAITVN(0);
        }
        const float4* L = buf[t & 1];
        const int R = w * 16 + lm;
        const int sw = R & 7;
        float4 f0 = L[R * 16 + ((2 * lg) ^ sw)];
        float4 f1 = L[R * 16 + ((2 * lg + 1) ^ sw)];
        float4 f2 = L[R * 16 + ((8 + 2 * lg) ^ sw)];
        float4 f3 = L[R * 16 + ((9 + 2 * lg) ^ sw)];
        bf16x8 alo = pack_bf8(f0, f1);
        bf16x8 ahi = pack_bf8(f2, f3);
        const int kq = t * 64 + w * 16 + lg * 4;
        const bool diag = (t == qt);
#pragma unroll
        for (int nt = 0; nt < 4; ++nt) {
            f32x4 acc = {0.f, 0.f, 0.f, 0.f};
            acc = MFMA(alo, qh0[nt].h, acc);
            acc = MFMA(alo, qh0[nt].l, acc);
            acc = MFMA(ahi, qh1[nt].h, acc);
            acc = MFMA(ahi, qh1[nt].l, acc);
            const int qe = q0 + nt * 16 + lm;
            float ov[4];
#pragma unroll
            for (int r = 0; r < 4; ++r)
                ov[r] = (!diag || (kq + r <= qe)) ? acc[r] : 0.f;
            float4 o;
            o.x = ov[0]; o.y = ov[1]; o.z = ov[2]; o.w = ov[3];
            *reinterpret_cast<float4*>(&P[((size_t)bh * SQ + qe) * SK + kq]) = o;
        }
    }
    // zero-fill tiles fully above the diagonal
    const float4 z = {0.f, 0.f, 0.f, 0.f};
#pragma unroll 1
    for (int t = nt_; t < 16; ++t) {
        const int kq = t * 64 + w * 16 + lg * 4;
#pragma unroll
        for (int nt = 0; nt < 4; ++nt) {
            const int qe = q0 + nt * 16 + lm;
            *reinterpret_cast<float4*>(&P[((size_t)bh * SQ + qe) * SK + kq]) = z;
        }
    }
}

// ---------------- K2: rel+exp -> e to P, fused PR: out = (Σ e·bigr_v)/rowsum.
// 4-stripe balanced q map; 2x-unrolled pipeline with named E/O prefetch sets.
__global__ __launch_bounds__(256) void k_rel_pv(const float* __restrict__ query,
                                                const float* __restrict__ bigr_k,
                                                const float* __restrict__ bigr_v,
                                                float* __restrict__ P,
                                                float* __restrict__ out,
                                                float* __restrict__ rs) {
    __shared__ float4 buf[2][1024];  // staging; reused for pr cross-wave reduce
    __shared__ float red[4][64];
    __shared__ float rsum[64];
    int q;
    {
        const int bid = blockIdx.x, c = bid & 255;
        switch (bid >> 8) {
            case 0:  q = 1023 - c; break;
            case 1:  q = c;        break;
            case 2:  q = 767 - c;  break;
            default: q = 256 + c;  break;
        }
    }
    const int KE = q + 1;
    const int nt_ = (KE + 63) >> 6;
    const int tid = threadIdx.x;
    const int w = tid >> 6, l = tid & 63;
    const int lm = l & 15, lg = l >> 4;

    Frag2 qh0[4], qh1[4];  // pre-scaled
    float* prow[4];
#pragma unroll
    for (int nt = 0; nt < 4; ++nt) {
        const int bh = nt * 16 + lm;
        const float* qrow = query + ((size_t)bh * SQ + q) * DH + lg * 8;
        qh0[nt] = load_split(qrow, SCALE);
        qh1[nt] = load_split(qrow + 32, SCALE);
        prow[nt] = P + ((size_t)bh * SQ + q) * SK;
    }
    const float* bk = bigr_k + (size_t)q * SK * DH;
    const float* bv = bigr_v + (size_t)q * SK * DH;
    float lsum[4] = {0.f, 0.f, 0.f, 0.f};
    f32x4 pr[4][4];  // [nt(bh group)][ntd(d group)]
#pragma unroll
    for (int a = 0; a < 4; ++a)
#pragma unroll
        for (int b = 0; b < 4; ++b) pr[a][b] = (f32x4){0.f, 0.f, 0.f, 0.f};

    // named prefetch sets (static indexing only -> stay in registers)
    float4 pcE[4], pcO[4];
    float bvE[16], bvO[16];

    auto loadPC = [&](float4 (&pc)[4], float (&bvr)[16], int t) {
        const int kq = t * 64 + w * 16 + lg * 4;
#pragma unroll
        for (int nt = 0; nt < 4; ++nt)
            pc[nt] = *reinterpret_cast<const float4*>(prow[nt] + kq);
        const int kbw = t * 64 + w * 16 + 4 * lg;
#pragma unroll
        for (int ntd = 0; ntd < 4; ++ntd)
#pragma unroll
            for (int j = 0; j < 4; ++j)
                bvr[ntd * 4 + j] = bv[(size_t)(kbw + j) * DH + ntd * 16 + lm];
    };

    auto compute = [&](int t, const float4 (&pc)[4], const float (&bvr)[16]) {
        const float4* L = buf[t & 1];
        const int R = w * 16 + lm;
        const int sw = R & 7;
        float4 f0 = L[R * 16 + ((2 * lg) ^ sw)];
        float4 f1 = L[R * 16 + ((2 * lg + 1) ^ sw)];
        float4 f2 = L[R * 16 + ((8 + 2 * lg) ^ sw)];
        float4 f3 = L[R * 16 + ((9 + 2 * lg) ^ sw)];
        bf16x8 alo = pack_bf8(f0, f1);
        bf16x8 ahi = pack_bf8(f2, f3);
        // stage 2 ahead into the buffer just consumed (LDS reads are done:
        // alo/ahi packing forced the lgkmcnt wait before this point)
        if (t + 2 < nt_) STAGE64(bk + (size_t)(t + 2) * 64 * DH, t & 1);
        bf16x8 bvf[4];
#pragma unroll
        for (int ntd = 0; ntd < 4; ++ntd) {
            ushort8 u;
#pragma unroll
            for (int j = 0; j < 4; ++j) u[j] = f2bf(bvr[ntd * 4 + j]);
            u[4] = 0; u[5] = 0; u[6] = 0; u[7] = 0;
            bvf[ntd] = __builtin_bit_cast(bf16x8, u);
        }
        const int kq = t * 64 + w * 16 + lg * 4;
#pragma unroll
        for (int nt = 0; nt < 4; ++nt) {
            f32x4 acc = {0.f, 0.f, 0.f, 0.f};
            acc = MFMA(alo, qh0[nt].h, acc);
            acc = MFMA(alo, qh0[nt].l, acc);
            acc = MFMA(ahi, qh1[nt].h, acc);
            acc = MFMA(ahi, qh1[nt].l, acc);
            const float4 c = pc[nt];
            float cv[4] = {c.x, c.y, c.z, c.w};
            float ov[4];
#pragma unroll
            for (int r = 0; r < 4; ++r) {
                float e = (kq + r < KE) ? __expf(cv[r] + acc[r]) : 0.f;
                ov[r] = e;
                lsum[nt] += e;
            }
            float4 o;
            o.x = ov[0]; o.y = ov[1]; o.z = ov[2]; o.w = ov[3];
            *reinterpret_cast<float4*>(prow[nt] + kq) = o;
            // PR accumulate: A = e quad in slots 0..3, K=16 (upper half zero)
            ushort8 ua;
#pragma unroll
            for (int j = 0; j < 4; ++j) ua[j] = f2bf(ov[j]);
            ua[4] = 0; ua[5] = 0; ua[6] = 0; ua[7] = 0;
            bf16x8 af = __builtin_bit_cast(bf16x8, ua);
#pragma unroll
            for (int ntd = 0; ntd < 4; ++ntd)
                pr[nt][ntd] = MFMA(af, bvf[ntd], pr[nt][ntd]);
        }
    };

    // prologue: stage(0), pcbv(0)->E, stage(1)
    STAGE64(bk, 0);
    loadPC(pcE, bvE, 0);
    if (nt_ > 1) STAGE64(bk + (size_t)64 * DH, 1);
    // steady state: WAITVN(28) keeps {pcbv(next)20 + stores(prev)4 + stage(next)4}
    // in flight while guaranteeing stage(cur)+pcbv(cur) retired (issue-order count).
#pragma unroll 1
    for (int t = 0; t < nt_; t += 2) {
        if (t + 1 < nt_) {
            loadPC(pcO, bvO, t + 1);
            WAITVN(28);
        } else {
            WAITVN(4);
        }
        compute(t, pcE, bvE);
        if (t + 1 < nt_) {
            if (t + 2 < nt_) {
                loadPC(pcE, bvE, t + 2);
                WAITVN(28);
            } else {
                WAITVN(4);
            }
            compute(t + 1, pcO, bvO);
        }
    }

    // ---- row-sum reduce -> rsum (recip) in LDS + rs in global ----
#pragma unroll
    for (int nt = 0; nt < 4; ++nt) {
        float v = lsum[nt];
        v += __shfl_xor(v, 16);
        v += __shfl_xor(v, 32);
        if (l < 16) red[w][nt * 16 + l] = v;
    }
    __syncthreads();  // red ready; also: all staging reads of buf complete
    if (tid < 64) {
        float nr = 1.0f / (red[0][tid] + red[1][tid] + red[2][tid] + red[3][tid]);
        rsum[tid] = nr;
        rs[(size_t)q * 64 + tid] = nr;
    }
    // ---- pr cross-wave reduce in buf (32 KB = 2 halves of 4096 floats) ----
    float* prbuf = reinterpret_cast<float*>(&buf[0][0]);
    if (w < 2) {
        float* dst = prbuf + w * 4096;
#pragma unroll
        for (int nt = 0; nt < 4; ++nt)
#pragma unroll
            for (int ntd = 0; ntd < 4; ++ntd)
#pragma unroll
                for (int r = 0; r < 4; ++r)
                    dst[(nt * 16 + lg * 4 + r) * 64 + ntd * 16 + lm] = pr[nt][ntd][r];
    }
    __syncthreads();  // halves written (w0,w1); rsum ready
    if (w >= 2) {
        float* dst = prbuf + (w - 2) * 4096;
#pragma unroll
        for (int nt = 0; nt < 4; ++nt)
#pragma unroll
            for (int ntd = 0; ntd < 4; ++ntd)
#pragma unroll
                for (int r = 0; r < 4; ++r)
                    dst[(nt * 16 + lg * 4 + r) * 64 + ntd * 16 + lm] += pr[nt][ntd][r];
    }
    __syncthreads();
    // ---- final: out[bh][q][d] = (half0 + half1) * rsum[bh] ----
#pragma unroll
    for (int i = 0; i < 4; ++i) {
        const int f4i = tid + i * 256;  // 0..1023 float4s
        float4 a = reinterpret_cast<const float4*>(prbuf)[f4i];
        float4 b = reinterpret_cast<const float4*>(prbuf)[1024 + f4i];
        const int fl = f4i * 4;
        const int bh = fl >> 6, d = fl & 63;
        const float nr = rsum[bh];
        float4 o = {(a.x + b.x) * nr, (a.y + b.y) * nr,
                    (a.z + b.z) * nr, (a.w + b.w) * nr};
        *reinterpret_cast<float4*>(&out[((size_t)bh * SQ + q) * DH + d]) = o;
    }
}

// ---------------- K3: Pn = e*recip written in place (final p_attn);
// out += Pn @ V. 1-D grid: qt = bid>>6, bh = bid&63 (balanced residency).
__global__ __launch_bounds__(256) void k_pv(float* __restrict__ P,
                                            const float* __restrict__ V,
                                            const float* __restrict__ rs,
                                            float* __restrict__ out) {
    const int bid = blockIdx.x;
    const int qt = bid >> 6;
    const int bh = bid & 63;
    const int tid = threadIdx.x;
    const int w = tid >> 6, l = tid & 63;
    const int lm = l & 15, lg = l >> 4;
    const int q0 = qt * 64 + w * 16;

    const float wrecip = rs[(size_t)(q0 + lm) * 64 + bh];
    float orecip[4];
#pragma unroll
    for (int r = 0; r < 4; ++r)
        orecip[r] = rs[(size_t)(q0 + lg * 4 + r) * 64 + bh];

    f32x4 acc[4] = {{0.f,0.f,0.f,0.f},{0.f,0.f,0.f,0.f},{0.f,0.f,0.f,0.f},{0.f,0.f,0.f,0.f}};
    const int kend = q0 + 16;
    for (int k0 = 0; k0 < kend; k0 += 32) {
        float* arow = P + ((size_t)bh * SQ + q0 + lm) * SK + k0 + lg * 8;
        float4 x0 = *reinterpret_cast<const float4*>(arow);
        float4 x1 = *reinterpret_cast<const float4*>(arow + 4);
        float4 y0 = {x0.x * wrecip, x0.y * wrecip, x0.z * wrecip, x0.w * wrecip};
        float4 y1 = {x1.x * wrecip, x1.y * wrecip, x1.z * wrecip, x1.w * wrecip};
        *reinterpret_cast<float4*>(arow) = y0;       // final normalized p_attn
        *reinterpret_cast<float4*>(arow + 4) = y1;
        bf16x8 a = pack_bf8(x0, x1);                 // unnormalized e
#pragma unroll
        for (int nt = 0; nt < 4; ++nt) {
            const float* bcol = V + ((size_t)bh * SK + k0 + lg * 8) * DH + nt * 16 + lm;
            bf16x8 b = load_bf8_strided(bcol, DH);
            acc[nt] = MFMA(a, b, acc[nt]);
        }
    }
#pragma unroll
    for (int nt = 0; nt < 4; ++nt)
#pragma unroll
        for (int r = 0; r < 4; ++r)
            out[((size_t)bh * SQ + q0 + lg * 4 + r) * DH + nt * 16 + lm] +=
                acc[nt][r] * orecip[r];
}

extern "C" void kernel_launch(void* const* d_in, const int* in_sizes, int n_in,
                              void* d_out, int out_size, void* d_ws, size_t ws_size,
                              hipStream_t stream) {
    const float* query  = (const float*)d_in[0];
    const float* key    = (const float*)d_in[1];
    const float* value  = (const float*)d_in[2];
    const float* bigr_k = (const float*)d_in[3];
    const float* bigr_v = (const float*)d_in[4];
    float* out = (float*)d_out;                       // BH*SQ*DH
    float* P   = out + (size_t)BH * SQ * DH;          // BH*SQ*SK
    float* rs  = (float*)d_ws;                        // [SQ][BH] recip = 256 KB

    k_scores<<<dim3(1024), 256, 0, stream>>>(query, key, P);
    k_rel_pv<<<dim3(SQ), 256, 0, stream>>>(query, bigr_k, bigr_v, P, out, rs);
    k_pv<<<dim3(1024), 256, 0, stream>>>(P, value, rs, out);
}

// Round 23
// 413.205 us; speedup vs baseline: 1.0194x; 1.0194x over previous
//
#include <hip/hip_runtime.h>
#include <hip/hip_bf16.h>

// Relative-position causal attention, B=4 H=16 Q=K=1024 D=64 (fp32 in/out).
// d_out = [output (BH*Q*D) | p_attn (BH*Q*K)] fp32.
// K1 k_scores<PACKED>: content scores; PACKED -> bf16 into dedicated ws buffer
//     (causal only, ~68 MB writes, NO aliasing with P); else R16 fp32 path.
// K2 k_rel_pv<PACKED>: R16 body; PACKED reads bf16 content from ws (8B loads)
//     + zero-fill epilogue for above-diagonal p_attn tiles.
// K3 k_pv: Pn = e*recip in place (final p_attn), out += Pn@V (R16, unchanged).

#define BH 64
#define SQ 1024
#define SK 1024
#define DH 64
#define SCALE 0.125f

typedef __attribute__((ext_vector_type(4))) float f32x4;
typedef __attribute__((ext_vector_type(8))) unsigned short ushort8;
typedef __attribute__((ext_vector_type(4))) unsigned short us4;
typedef __attribute__((ext_vector_type(8))) __bf16 bf16x8;

static __device__ inline unsigned short f2bf(float x) {
    unsigned u = __float_as_uint(x);
    unsigned r = u + 0x7FFFu + ((u >> 16) & 1u);
    return (unsigned short)(r >> 16);
}
static __device__ inline float bf2f(unsigned short s) {
    return __uint_as_float(((unsigned)s) << 16);
}

struct Frag2 { bf16x8 h, l; };

// Load 8 fp32, scale, split into hi/lo bf16 fragments (hi+lo == scaled value).
static __device__ inline Frag2 load_split(const float* __restrict__ p, float scale) {
    float4 x0 = *reinterpret_cast<const float4*>(p);
    float4 x1 = *reinterpret_cast<const float4*>(p + 4);
    float v[8] = {x0.x, x0.y, x0.z, x0.w, x1.x, x1.y, x1.z, x1.w};
    ushort8 uh, ul;
#pragma unroll
    for (int j = 0; j < 8; ++j) {
        float s = v[j] * scale;
        unsigned short h = f2bf(s);
        float r = s - bf2f(h);
        uh[j] = h;
        ul[j] = f2bf(r);
    }
    Frag2 f;
    f.h = __builtin_bit_cast(bf16x8, uh);
    f.l = __builtin_bit_cast(bf16x8, ul);
    return f;
}

static __device__ inline bf16x8 pack_bf8(float4 x0, float4 x1) {
    float v[8] = {x0.x, x0.y, x0.z, x0.w, x1.x, x1.y, x1.z, x1.w};
    ushort8 u;
#pragma unroll
    for (int j = 0; j < 8; ++j) u[j] = f2bf(v[j]);
    return __builtin_bit_cast(bf16x8, u);
}

static __device__ inline bf16x8 load_bf8(const float* __restrict__ p) {
    float4 x0 = *reinterpret_cast<const float4*>(p);
    float4 x1 = *reinterpret_cast<const float4*>(p + 4);
    return pack_bf8(x0, x1);
}

static __device__ inline bf16x8 load_bf8_strided(const float* __restrict__ p, int stride) {
    ushort8 u;
#pragma unroll
    for (int j = 0; j < 8; ++j) u[j] = f2bf(p[(size_t)j * stride]);
    return __builtin_bit_cast(bf16x8, u);
}

#define MFMA(a, b, c) __builtin_amdgcn_mfma_f32_16x16x32_bf16((a), (b), (c), 0, 0, 0)

// async global -> LDS, 16B per lane; lds dest is wave-uniform base + lane*16
#define GLLD(g, s)                                                              \
    __builtin_amdgcn_global_load_lds(                                           \
        (const __attribute__((address_space(1))) void*)(g),                     \
        (__attribute__((address_space(3))) void*)(s), 16, 0, 0)

// stage a 64x64 fp32 tile (rows at src0 + row*DH) into buf[b]; WAVE-PRIVATE:
// wave w stages rows [w*16, w*16+16) and later reads only those rows.
// source pre-swizzled (chunk ^= row&7) so linear LDS + swizzled reads match.
#define STAGE64(src0, b)                                                        \
    do {                                                                        \
        _Pragma("unroll")                                                       \
        for (int j_ = 0; j_ < 4; ++j_) {                                        \
            const int idx_ = w * 256 + j_ * 64 + l;                             \
            const int row_ = idx_ >> 4;                                         \
            const int g_ = (idx_ & 15) ^ (row_ & 7);                            \
            GLLD((src0) + (size_t)row_ * DH + g_ * 4,                           \
                 &buf[b][w * 256 + j_ * 64]);                                   \
        }                                                                       \
    } while (0)

#define WAITVN(n)                                                               \
    do {                                                                        \
        asm volatile("s_waitcnt vmcnt(" #n ")" ::: "memory");                   \
        __builtin_amdgcn_sched_barrier(0);                                      \
    } while (0)

// ---------------- K1: content scores Q@K^T * scale. PACKED: bf16 -> cb (ws),
// causal tiles only. !PACKED: fp32 -> P with zero-fill (R16).
// 1-D grid: qt = bid>>6 (high bits), bh = bid&63.
template <bool PACKED>
__global__ __launch_bounds__(256, 4) void k_scores(const float* __restrict__ qp,
                                                   const float* __restrict__ kp,
                                                   float* __restrict__ P,
                                                   unsigned short* __restrict__ cb) {
    __shared__ float4 buf[2][1024];
    const int bid = blockIdx.x;
    const int qt = bid >> 6;
    const int bh = bid & 63;
    const int tid = threadIdx.x;
    const int w = tid >> 6, l = tid & 63;
    const int lm = l & 15, lg = l >> 4;
    const int q0 = qt * 64;

    Frag2 qh0[4], qh1[4];  // pre-scaled by SCALE
#pragma unroll
    for (int nt = 0; nt < 4; ++nt) {
        const float* qrow = qp + ((size_t)bh * SQ + q0 + nt * 16 + lm) * DH + lg * 8;
        qh0[nt] = load_split(qrow, SCALE);
        qh1[nt] = load_split(qrow + 32, SCALE);
    }
    const float* kb = kp + (size_t)bh * SK * DH;
    const int nt_ = qt + 1;

    STAGE64(kb, 0);
#pragma unroll 1
    for (int t = 0; t < nt_; ++t) {
        if (t + 1 < nt_) {
            STAGE64(kb + (size_t)(t + 1) * 64 * DH, (t + 1) & 1);
            WAITVN(4);  // stage(t)+stores(t-1) landed; stage(t+1) in flight
        } else {
            WAITVN(0);
        }
        const float4* L = buf[t & 1];
        const int R = w * 16 + lm;
        const int sw = R & 7;
        float4 f0 = L[R * 16 + ((2 * lg) ^ sw)];
        float4 f1 = L[R * 16 + ((2 * lg + 1) ^ sw)];
        float4 f2 = L[R * 16 + ((8 + 2 * lg) ^ sw)];
        float4 f3 = L[R * 16 + ((9 + 2 * lg) ^ sw)];
        bf16x8 alo = pack_bf8(f0, f1);
        bf16x8 ahi = pack_bf8(f2, f3);
        const int kq = t * 64 + w * 16 + lg * 4;
        const bool diag = (t == qt);
#pragma unroll
        for (int nt = 0; nt < 4; ++nt) {
            f32x4 acc = {0.f, 0.f, 0.f, 0.f};
            acc = MFMA(alo, qh0[nt].h, acc);
            acc = MFMA(alo, qh0[nt].l, acc);
            acc = MFMA(ahi, qh1[nt].h, acc);
            acc = MFMA(ahi, qh1[nt].l, acc);
            const int qe = q0 + nt * 16 + lm;
            if (PACKED) {
                us4 o;
#pragma unroll
                for (int r = 0; r < 4; ++r)
                    o[r] = f2bf((!diag || (kq + r <= qe)) ? acc[r] : 0.f);
                *reinterpret_cast<us4*>(&cb[((size_t)bh * SQ + qe) * SK + kq]) = o;
            } else {
                float ov[4];
#pragma unroll
                for (int r = 0; r < 4; ++r)
                    ov[r] = (!diag || (kq + r <= qe)) ? acc[r] : 0.f;
                float4 o;
                o.x = ov[0]; o.y = ov[1]; o.z = ov[2]; o.w = ov[3];
                *reinterpret_cast<float4*>(&P[((size_t)bh * SQ + qe) * SK + kq]) = o;
            }
        }
    }
    if (!PACKED) {
        // zero-fill tiles fully above the diagonal
        const float4 z = {0.f, 0.f, 0.f, 0.f};
#pragma unroll 1
        for (int t = nt_; t < 16; ++t) {
            const int kq = t * 64 + w * 16 + lg * 4;
#pragma unroll
            for (int nt = 0; nt < 4; ++nt) {
                const int qe = q0 + nt * 16 + lm;
                *reinterpret_cast<float4*>(&P[((size_t)bh * SQ + qe) * SK + kq]) = z;
            }
        }
    }
}

// ---------------- K2: rel+exp -> e to P, fused PR: out = (Σ e·bigr_v)/rowsum.
// 4-stripe balanced q map. PACKED: content from cb (separate buffer, race-free)
// + zero-fill epilogue. !PACKED: content from P (R16).
template <bool PACKED>
__global__ __launch_bounds__(256) void k_rel_pv(const float* __restrict__ query,
                                                const float* __restrict__ bigr_k,
                                                const float* __restrict__ bigr_v,
                                                float* __restrict__ P,
                                                const unsigned short* __restrict__ cb,
                                                float* __restrict__ out,
                                                float* __restrict__ rs) {
    __shared__ float4 buf[2][1024];  // staging; reused for pr cross-wave reduce
    __shared__ float red[4][64];
    __shared__ float rsum[64];
    int q;
    {
        const int bid = blockIdx.x, c = bid & 255;
        switch (bid >> 8) {
            case 0:  q = 1023 - c; break;
            case 1:  q = c;        break;
            case 2:  q = 767 - c;  break;
            default: q = 256 + c;  break;
        }
    }
    const int KE = q + 1;
    const int nt_ = (KE + 63) >> 6;
    const int tid = threadIdx.x;
    const int w = tid >> 6, l = tid & 63;
    const int lm = l & 15, lg = l >> 4;

    Frag2 qh0[4], qh1[4];  // pre-scaled
    float* prow[4];
    const unsigned short* crow[4];
#pragma unroll
    for (int nt = 0; nt < 4; ++nt) {
        const int bh = nt * 16 + lm;
        const float* qrow = query + ((size_t)bh * SQ + q) * DH + lg * 8;
        qh0[nt] = load_split(qrow, SCALE);
        qh1[nt] = load_split(qrow + 32, SCALE);
        prow[nt] = P + ((size_t)bh * SQ + q) * SK;
        crow[nt] = cb + ((size_t)bh * SQ + q) * SK;
    }
    const float* bk = bigr_k + (size_t)q * SK * DH;
    const float* bv = bigr_v + (size_t)q * SK * DH;
    float lsum[4] = {0.f, 0.f, 0.f, 0.f};
    f32x4 pr[4][4];  // [nt(bh group)][ntd(d group)]
#pragma unroll
    for (int a = 0; a < 4; ++a)
#pragma unroll
        for (int b = 0; b < 4; ++b) pr[a][b] = (f32x4){0.f, 0.f, 0.f, 0.f};

    STAGE64(bk, 0);
#pragma unroll 1
    for (int t = 0; t < nt_; ++t) {
        const int kq = t * 64 + w * 16 + lg * 4;
        us4 pcp[4];
        float4 pcf[4];
#pragma unroll
        for (int nt = 0; nt < 4; ++nt) {
            if (PACKED)
                pcp[nt] = *reinterpret_cast<const us4*>(crow[nt] + kq);
            else
                pcf[nt] = *reinterpret_cast<const float4*>(prow[nt] + kq);
        }
        // bigr_v B-fragments for this wave's 16-k stripe (consumed this iter)
        bf16x8 bvf[4];
        {
            const int kbw = t * 64 + w * 16 + 4 * lg;
#pragma unroll
            for (int ntd = 0; ntd < 4; ++ntd) {
                ushort8 u;
#pragma unroll
                for (int j = 0; j < 4; ++j)
                    u[j] = f2bf(bv[(size_t)(kbw + j) * DH + ntd * 16 + lm]);
                u[4] = 0; u[5] = 0; u[6] = 0; u[7] = 0;
                bvf[ntd] = __builtin_bit_cast(bf16x8, u);
            }
        }
        if (t + 1 < nt_) {
            STAGE64(bk + (size_t)(t + 1) * 64 * DH, (t + 1) & 1);
            WAITVN(4);  // stage(t)+pc+bv landed; stage(t+1) in flight
        } else {
            WAITVN(0);
        }
        const float4* L = buf[t & 1];
        const int R = w * 16 + lm;
        const int sw = R & 7;
        float4 f0 = L[R * 16 + ((2 * lg) ^ sw)];
        float4 f1 = L[R * 16 + ((2 * lg + 1) ^ sw)];
        float4 f2 = L[R * 16 + ((8 + 2 * lg) ^ sw)];
        float4 f3 = L[R * 16 + ((9 + 2 * lg) ^ sw)];
        bf16x8 alo = pack_bf8(f0, f1);
        bf16x8 ahi = pack_bf8(f2, f3);
#pragma unroll
        for (int nt = 0; nt < 4; ++nt) {
            f32x4 acc = {0.f, 0.f, 0.f, 0.f};
            acc = MFMA(alo, qh0[nt].h, acc);
            acc = MFMA(alo, qh0[nt].l, acc);
            acc = MFMA(ahi, qh1[nt].h, acc);
            acc = MFMA(ahi, qh1[nt].l, acc);
            float ov[4];
#pragma unroll
            for (int r = 0; r < 4; ++r) {
                const float c = PACKED ? bf2f(pcp[nt][r])
                                       : ((const float*)&pcf[nt])[r];
                float e = (kq + r < KE) ? __expf(c + acc[r]) : 0.f;
                ov[r] = e;
                lsum[nt] += e;
            }
            float4 o;
            o.x = ov[0]; o.y = ov[1]; o.z = ov[2]; o.w = ov[3];
            *reinterpret_cast<float4*>(prow[nt] + kq) = o;
            // PR accumulate: A = e (this lane's quad in slots 0..3), K=16 via
            // zeroed upper half; D[m=bh_in=lg*4+r][n=d_in=lm].
            ushort8 ua;
#pragma unroll
            for (int j = 0; j < 4; ++j) ua[j] = f2bf(ov[j]);
            ua[4] = 0; ua[5] = 0; ua[6] = 0; ua[7] = 0;
            bf16x8 af = __builtin_bit_cast(bf16x8, ua);
#pragma unroll
            for (int ntd = 0; ntd < 4; ++ntd)
                pr[nt][ntd] = MFMA(af, bvf[ntd], pr[nt][ntd]);
        }
    }

    if (PACKED) {
        // zero-fill above-diagonal tiles (final p_attn zeros); work size
        // anti-correlated with causal compute -> per-CU balance preserved
        const float4 z = {0.f, 0.f, 0.f, 0.f};
#pragma unroll 1
        for (int t = nt_; t < 16; ++t) {
            const int kq = t * 64 + w * 16 + lg * 4;
#pragma unroll
            for (int nt = 0; nt < 4; ++nt)
                *reinterpret_cast<float4*>(prow[nt] + kq) = z;
        }
    }

    // ---- row-sum reduce -> rsum (recip) in LDS + rs in global ----
#pragma unroll
    for (int nt = 0; nt < 4; ++nt) {
        float v = lsum[nt];
        v += __shfl_xor(v, 16);
        v += __shfl_xor(v, 32);
        if (l < 16) red[w][nt * 16 + l] = v;
    }
    __syncthreads();  // red ready; also: all staging reads of buf complete
    if (tid < 64) {
        float nr = 1.0f / (red[0][tid] + red[1][tid] + red[2][tid] + red[3][tid]);
        rsum[tid] = nr;
        rs[(size_t)q * 64 + tid] = nr;
    }
    // ---- pr cross-wave reduce in buf (32 KB = 2 halves of 4096 floats) ----
    float* prbuf = reinterpret_cast<float*>(&buf[0][0]);
    if (w < 2) {
        float* dst = prbuf + w * 4096;
#pragma unroll
        for (int nt = 0; nt < 4; ++nt)
#pragma unroll
            for (int ntd = 0; ntd < 4; ++ntd)
#pragma unroll
                for (int r = 0; r < 4; ++r)
                    dst[(nt * 16 + lg * 4 + r) * 64 + ntd * 16 + lm] = pr[nt][ntd][r];
    }
    __syncthreads();  // halves written (w0,w1); rsum ready
    if (w >= 2) {
        float* dst = prbuf + (w - 2) * 4096;
#pragma unroll
        for (int nt = 0; nt < 4; ++nt)
#pragma unroll
            for (int ntd = 0; ntd < 4; ++ntd)
#pragma unroll
                for (int r = 0; r < 4; ++r)
                    dst[(nt * 16 + lg * 4 + r) * 64 + ntd * 16 + lm] += pr[nt][ntd][r];
    }
    __syncthreads();
    // ---- final: out[bh][q][d] = (half0 + half1) * rsum[bh] ----
#pragma unroll
    for (int i = 0; i < 4; ++i) {
        const int f4i = tid + i * 256;  // 0..1023 float4s
        float4 a = reinterpret_cast<const float4*>(prbuf)[f4i];
        float4 b = reinterpret_cast<const float4*>(prbuf)[1024 + f4i];
        const int fl = f4i * 4;
        const int bh = fl >> 6, d = fl & 63;
        const float nr = rsum[bh];
        float4 o = {(a.x + b.x) * nr, (a.y + b.y) * nr,
                    (a.z + b.z) * nr, (a.w + b.w) * nr};
        *reinterpret_cast<float4*>(&out[((size_t)bh * SQ + q) * DH + d]) = o;
    }
}

// ---------------- K3: Pn = e*recip written in place (final p_attn);
// out += Pn @ V. 1-D grid: qt = bid>>6, bh = bid&63 (balanced residency).
__global__ __launch_bounds__(256) void k_pv(float* __restrict__ P,
                                            const float* __restrict__ V,
                                            const float* __restrict__ rs,
                                            float* __restrict__ out) {
    const int bid = blockIdx.x;
    const int qt = bid >> 6;
    const int bh = bid & 63;
    const int tid = threadIdx.x;
    const int w = tid >> 6, l = tid & 63;
    const int lm = l & 15, lg = l >> 4;
    const int q0 = qt * 64 + w * 16;

    const float wrecip = rs[(size_t)(q0 + lm) * 64 + bh];
    float orecip[4];
#pragma unroll
    for (int r = 0; r < 4; ++r)
        orecip[r] = rs[(size_t)(q0 + lg * 4 + r) * 64 + bh];

    f32x4 acc[4] = {{0.f,0.f,0.f,0.f},{0.f,0.f,0.f,0.f},{0.f,0.f,0.f,0.f},{0.f,0.f,0.f,0.f}};
    const int kend = q0 + 16;
    for (int k0 = 0; k0 < kend; k0 += 32) {
        float* arow = P + ((size_t)bh * SQ + q0 + lm) * SK + k0 + lg * 8;
        float4 x0 = *reinterpret_cast<const float4*>(arow);
        float4 x1 = *reinterpret_cast<const float4*>(arow + 4);
        float4 y0 = {x0.x * wrecip, x0.y * wrecip, x0.z * wrecip, x0.w * wrecip};
        float4 y1 = {x1.x * wrecip, x1.y * wrecip, x1.z * wrecip, x1.w * wrecip};
        *reinterpret_cast<float4*>(arow) = y0;       // final normalized p_attn
        *reinterpret_cast<float4*>(arow + 4) = y1;
        bf16x8 a = pack_bf8(x0, x1);                 // unnormalized e
#pragma unroll
        for (int nt = 0; nt < 4; ++nt) {
            const float* bcol = V + ((size_t)bh * SK + k0 + lg * 8) * DH + nt * 16 + lm;
            bf16x8 b = load_bf8_strided(bcol, DH);
            acc[nt] = MFMA(a, b, acc[nt]);
        }
    }
#pragma unroll
    for (int nt = 0; nt < 4; ++nt)
#pragma unroll
        for (int r = 0; r < 4; ++r)
            out[((size_t)bh * SQ + q0 + lg * 4 + r) * DH + nt * 16 + lm] +=
                acc[nt][r] * orecip[r];
}

extern "C" void kernel_launch(void* const* d_in, const int* in_sizes, int n_in,
                              void* d_out, int out_size, void* d_ws, size_t ws_size,
                              hipStream_t stream) {
    const float* query  = (const float*)d_in[0];
    const float* key    = (const float*)d_in[1];
    const float* value  = (const float*)d_in[2];
    const float* bigr_k = (const float*)d_in[3];
    const float* bigr_v = (const float*)d_in[4];
    float* out = (float*)d_out;                       // BH*SQ*DH
    float* P   = out + (size_t)BH * SQ * DH;          // BH*SQ*SK
    float* rs  = (float*)d_ws;                        // [SQ][BH] recip = 256 KB
    unsigned short* cb = (unsigned short*)(rs + (size_t)SQ * 64);  // 128 MB bf16
    const bool packed =
        ws_size >= (size_t)SQ * 64 * 4 + (size_t)BH * SQ * SK * 2;

    if (packed) {
        k_scores<true><<<dim3(1024), 256, 0, stream>>>(query, key, P, cb);
        k_rel_pv<true><<<dim3(SQ), 256, 0, stream>>>(query, bigr_k, bigr_v, P, cb, out, rs);
    } else {
        k_scores<false><<<dim3(1024), 256, 0, stream>>>(query, key, P, cb);
        k_rel_pv<false><<<dim3(SQ), 256, 0, stream>>>(query, bigr_k, bigr_v, P, cb, out, rs);
    }
    k_pv<<<dim3(1024), 256, 0, stream>>>(P, value, rs, out);
}

// Round 24
// 387.780 us; speedup vs baseline: 1.0863x; 1.0656x over previous
//
#include <hip/hip_runtime.h>
#include <hip/hip_bf16.h>

// Relative-position causal attention, B=4 H=16 Q=K=1024 D=64 (fp32 in/out).
// d_out = [output (BH*Q*D) | p_attn (BH*Q*K)] fp32.
// K1 k_scores<PACKED>: content scores -> bf16 cb (ws, causal only) AND fp32
//     zero-fill of above-diagonal P tiles (streams free under glld pipeline).
// K2 k_rel_pv<PACKED>: rel+exp -> e to P + fused PR; packed 8B content reads;
//     NO epilogue (zeros already in P).  Fallback: R16 fp32 path.
// K3 k_pv: Pn = e*recip in place (final p_attn), out += Pn@V (R16, unchanged).

#define BH 64
#define SQ 1024
#define SK 1024
#define DH 64
#define SCALE 0.125f

typedef __attribute__((ext_vector_type(4))) float f32x4;
typedef __attribute__((ext_vector_type(8))) unsigned short ushort8;
typedef __attribute__((ext_vector_type(4))) unsigned short us4;
typedef __attribute__((ext_vector_type(8))) __bf16 bf16x8;

static __device__ inline unsigned short f2bf(float x) {
    unsigned u = __float_as_uint(x);
    unsigned r = u + 0x7FFFu + ((u >> 16) & 1u);
    return (unsigned short)(r >> 16);
}
static __device__ inline float bf2f(unsigned short s) {
    return __uint_as_float(((unsigned)s) << 16);
}

struct Frag2 { bf16x8 h, l; };

// Load 8 fp32, scale, split into hi/lo bf16 fragments (hi+lo == scaled value).
static __device__ inline Frag2 load_split(const float* __restrict__ p, float scale) {
    float4 x0 = *reinterpret_cast<const float4*>(p);
    float4 x1 = *reinterpret_cast<const float4*>(p + 4);
    float v[8] = {x0.x, x0.y, x0.z, x0.w, x1.x, x1.y, x1.z, x1.w};
    ushort8 uh, ul;
#pragma unroll
    for (int j = 0; j < 8; ++j) {
        float s = v[j] * scale;
        unsigned short h = f2bf(s);
        float r = s - bf2f(h);
        uh[j] = h;
        ul[j] = f2bf(r);
    }
    Frag2 f;
    f.h = __builtin_bit_cast(bf16x8, uh);
    f.l = __builtin_bit_cast(bf16x8, ul);
    return f;
}

static __device__ inline bf16x8 pack_bf8(float4 x0, float4 x1) {
    float v[8] = {x0.x, x0.y, x0.z, x0.w, x1.x, x1.y, x1.z, x1.w};
    ushort8 u;
#pragma unroll
    for (int j = 0; j < 8; ++j) u[j] = f2bf(v[j]);
    return __builtin_bit_cast(bf16x8, u);
}

static __device__ inline bf16x8 load_bf8(const float* __restrict__ p) {
    float4 x0 = *reinterpret_cast<const float4*>(p);
    float4 x1 = *reinterpret_cast<const float4*>(p + 4);
    return pack_bf8(x0, x1);
}

static __device__ inline bf16x8 load_bf8_strided(const float* __restrict__ p, int stride) {
    ushort8 u;
#pragma unroll
    for (int j = 0; j < 8; ++j) u[j] = f2bf(p[(size_t)j * stride]);
    return __builtin_bit_cast(bf16x8, u);
}

#define MFMA(a, b, c) __builtin_amdgcn_mfma_f32_16x16x32_bf16((a), (b), (c), 0, 0, 0)

// async global -> LDS, 16B per lane; lds dest is wave-uniform base + lane*16
#define GLLD(g, s)                                                              \
    __builtin_amdgcn_global_load_lds(                                           \
        (const __attribute__((address_space(1))) void*)(g),                     \
        (__attribute__((address_space(3))) void*)(s), 16, 0, 0)

// stage a 64x64 fp32 tile (rows at src0 + row*DH) into buf[b]; WAVE-PRIVATE:
// wave w stages rows [w*16, w*16+16) and later reads only those rows.
// source pre-swizzled (chunk ^= row&7) so linear LDS + swizzled reads match.
#define STAGE64(src0, b)                                                        \
    do {                                                                        \
        _Pragma("unroll")                                                       \
        for (int j_ = 0; j_ < 4; ++j_) {                                        \
            const int idx_ = w * 256 + j_ * 64 + l;                             \
            const int row_ = idx_ >> 4;                                         \
            const int g_ = (idx_ & 15) ^ (row_ & 7);                            \
            GLLD((src0) + (size_t)row_ * DH + g_ * 4,                           \
                 &buf[b][w * 256 + j_ * 64]);                                   \
        }                                                                       \
    } while (0)

#define WAITVN(n)                                                               \
    do {                                                                        \
        asm volatile("s_waitcnt vmcnt(" #n ")" ::: "memory");                   \
        __builtin_amdgcn_sched_barrier(0);                                      \
    } while (0)

// ---------------- K1: content scores Q@K^T * scale. PACKED: bf16 causal -> cb
// AND fp32 zero-fill of above-diagonal P tiles. !PACKED: R16 fp32 path.
// 1-D grid: qt = bid>>6 (high bits), bh = bid&63.
template <bool PACKED>
__global__ __launch_bounds__(256, 4) void k_scores(const float* __restrict__ qp,
                                                   const float* __restrict__ kp,
                                                   float* __restrict__ P,
                                                   unsigned short* __restrict__ cb) {
    __shared__ float4 buf[2][1024];
    const int bid = blockIdx.x;
    const int qt = bid >> 6;
    const int bh = bid & 63;
    const int tid = threadIdx.x;
    const int w = tid >> 6, l = tid & 63;
    const int lm = l & 15, lg = l >> 4;
    const int q0 = qt * 64;

    Frag2 qh0[4], qh1[4];  // pre-scaled by SCALE
#pragma unroll
    for (int nt = 0; nt < 4; ++nt) {
        const float* qrow = qp + ((size_t)bh * SQ + q0 + nt * 16 + lm) * DH + lg * 8;
        qh0[nt] = load_split(qrow, SCALE);
        qh1[nt] = load_split(qrow + 32, SCALE);
    }
    const float* kb = kp + (size_t)bh * SK * DH;
    const int nt_ = qt + 1;

    STAGE64(kb, 0);
#pragma unroll 1
    for (int t = 0; t < nt_; ++t) {
        if (t + 1 < nt_) {
            STAGE64(kb + (size_t)(t + 1) * 64 * DH, (t + 1) & 1);
            WAITVN(4);  // stage(t)+stores(t-1) landed; stage(t+1) in flight
        } else {
            WAITVN(0);
        }
        const float4* L = buf[t & 1];
        const int R = w * 16 + lm;
        const int sw = R & 7;
        float4 f0 = L[R * 16 + ((2 * lg) ^ sw)];
        float4 f1 = L[R * 16 + ((2 * lg + 1) ^ sw)];
        float4 f2 = L[R * 16 + ((8 + 2 * lg) ^ sw)];
        float4 f3 = L[R * 16 + ((9 + 2 * lg) ^ sw)];
        bf16x8 alo = pack_bf8(f0, f1);
        bf16x8 ahi = pack_bf8(f2, f3);
        const int kq = t * 64 + w * 16 + lg * 4;
        const bool diag = (t == qt);
#pragma unroll
        for (int nt = 0; nt < 4; ++nt) {
            f32x4 acc = {0.f, 0.f, 0.f, 0.f};
            acc = MFMA(alo, qh0[nt].h, acc);
            acc = MFMA(alo, qh0[nt].l, acc);
            acc = MFMA(ahi, qh1[nt].h, acc);
            acc = MFMA(ahi, qh1[nt].l, acc);
            const int qe = q0 + nt * 16 + lm;
            if (PACKED) {
                us4 o;
#pragma unroll
                for (int r = 0; r < 4; ++r)
                    o[r] = f2bf((!diag || (kq + r <= qe)) ? acc[r] : 0.f);
                *reinterpret_cast<us4*>(&cb[((size_t)bh * SQ + qe) * SK + kq]) = o;
            } else {
                float ov[4];
#pragma unroll
                for (int r = 0; r < 4; ++r)
                    ov[r] = (!diag || (kq + r <= qe)) ? acc[r] : 0.f;
                float4 o;
                o.x = ov[0]; o.y = ov[1]; o.z = ov[2]; o.w = ov[3];
                *reinterpret_cast<float4*>(&P[((size_t)bh * SQ + qe) * SK + kq]) = o;
            }
        }
    }
    // zero-fill P tiles fully above the diagonal (both paths: final p_attn zeros)
    const float4 z = {0.f, 0.f, 0.f, 0.f};
#pragma unroll 1
    for (int t = nt_; t < 16; ++t) {
        const int kq = t * 64 + w * 16 + lg * 4;
#pragma unroll
        for (int nt = 0; nt < 4; ++nt) {
            const int qe = q0 + nt * 16 + lm;
            *reinterpret_cast<float4*>(&P[((size_t)bh * SQ + qe) * SK + kq]) = z;
        }
    }
}

// ---------------- K2: rel+exp -> e to P, fused PR: out = (Σ e·bigr_v)/rowsum.
// 4-stripe balanced q map. PACKED: content from cb (8B loads); no epilogue.
template <bool PACKED>
__global__ __launch_bounds__(256) void k_rel_pv(const float* __restrict__ query,
                                                const float* __restrict__ bigr_k,
                                                const float* __restrict__ bigr_v,
                                                float* __restrict__ P,
                                                const unsigned short* __restrict__ cb,
                                                float* __restrict__ out,
                                                float* __restrict__ rs) {
    __shared__ float4 buf[2][1024];  // staging; reused for pr cross-wave reduce
    __shared__ float red[4][64];
    __shared__ float rsum[64];
    int q;
    {
        const int bid = blockIdx.x, c = bid & 255;
        switch (bid >> 8) {
            case 0:  q = 1023 - c; break;
            case 1:  q = c;        break;
            case 2:  q = 767 - c;  break;
            default: q = 256 + c;  break;
        }
    }
    const int KE = q + 1;
    const int nt_ = (KE + 63) >> 6;
    const int tid = threadIdx.x;
    const int w = tid >> 6, l = tid & 63;
    const int lm = l & 15, lg = l >> 4;

    Frag2 qh0[4], qh1[4];  // pre-scaled
    float* prow[4];
    const unsigned short* crow[4];
#pragma unroll
    for (int nt = 0; nt < 4; ++nt) {
        const int bh = nt * 16 + lm;
        const float* qrow = query + ((size_t)bh * SQ + q) * DH + lg * 8;
        qh0[nt] = load_split(qrow, SCALE);
        qh1[nt] = load_split(qrow + 32, SCALE);
        prow[nt] = P + ((size_t)bh * SQ + q) * SK;
        crow[nt] = cb + ((size_t)bh * SQ + q) * SK;
    }
    const float* bk = bigr_k + (size_t)q * SK * DH;
    const float* bv = bigr_v + (size_t)q * SK * DH;
    float lsum[4] = {0.f, 0.f, 0.f, 0.f};
    f32x4 pr[4][4];  // [nt(bh group)][ntd(d group)]
#pragma unroll
    for (int a = 0; a < 4; ++a)
#pragma unroll
        for (int b = 0; b < 4; ++b) pr[a][b] = (f32x4){0.f, 0.f, 0.f, 0.f};

    STAGE64(bk, 0);
#pragma unroll 1
    for (int t = 0; t < nt_; ++t) {
        const int kq = t * 64 + w * 16 + lg * 4;
        us4 pcp[4];
        float4 pcf[4];
#pragma unroll
        for (int nt = 0; nt < 4; ++nt) {
            if (PACKED)
                pcp[nt] = *reinterpret_cast<const us4*>(crow[nt] + kq);
            else
                pcf[nt] = *reinterpret_cast<const float4*>(prow[nt] + kq);
        }
        // bigr_v B-fragments for this wave's 16-k stripe (consumed this iter)
        bf16x8 bvf[4];
        {
            const int kbw = t * 64 + w * 16 + 4 * lg;
#pragma unroll
            for (int ntd = 0; ntd < 4; ++ntd) {
                ushort8 u;
#pragma unroll
                for (int j = 0; j < 4; ++j)
                    u[j] = f2bf(bv[(size_t)(kbw + j) * DH + ntd * 16 + lm]);
                u[4] = 0; u[5] = 0; u[6] = 0; u[7] = 0;
                bvf[ntd] = __builtin_bit_cast(bf16x8, u);
            }
        }
        if (t + 1 < nt_) {
            STAGE64(bk + (size_t)(t + 1) * 64 * DH, (t + 1) & 1);
            WAITVN(4);  // stage(t)+pc+bv landed; stage(t+1) in flight
        } else {
            WAITVN(0);
        }
        const float4* L = buf[t & 1];
        const int R = w * 16 + lm;
        const int sw = R & 7;
        float4 f0 = L[R * 16 + ((2 * lg) ^ sw)];
        float4 f1 = L[R * 16 + ((2 * lg + 1) ^ sw)];
        float4 f2 = L[R * 16 + ((8 + 2 * lg) ^ sw)];
        float4 f3 = L[R * 16 + ((9 + 2 * lg) ^ sw)];
        bf16x8 alo = pack_bf8(f0, f1);
        bf16x8 ahi = pack_bf8(f2, f3);
#pragma unroll
        for (int nt = 0; nt < 4; ++nt) {
            f32x4 acc = {0.f, 0.f, 0.f, 0.f};
            acc = MFMA(alo, qh0[nt].h, acc);
            acc = MFMA(alo, qh0[nt].l, acc);
            acc = MFMA(ahi, qh1[nt].h, acc);
            acc = MFMA(ahi, qh1[nt].l, acc);
            float ov[4];
#pragma unroll
            for (int r = 0; r < 4; ++r) {
                const float c = PACKED ? bf2f(pcp[nt][r])
                                       : ((const float*)&pcf[nt])[r];
                float e = (kq + r < KE) ? __expf(c + acc[r]) : 0.f;
                ov[r] = e;
                lsum[nt] += e;
            }
            float4 o;
            o.x = ov[0]; o.y = ov[1]; o.z = ov[2]; o.w = ov[3];
            *reinterpret_cast<float4*>(prow[nt] + kq) = o;
            // PR accumulate: A = e (this lane's quad in slots 0..3), K=16 via
            // zeroed upper half; D[m=bh_in=lg*4+r][n=d_in=lm].
            ushort8 ua;
#pragma unroll
            for (int j = 0; j < 4; ++j) ua[j] = f2bf(ov[j]);
            ua[4] = 0; ua[5] = 0; ua[6] = 0; ua[7] = 0;
            bf16x8 af = __builtin_bit_cast(bf16x8, ua);
#pragma unroll
            for (int ntd = 0; ntd < 4; ++ntd)
                pr[nt][ntd] = MFMA(af, bvf[ntd], pr[nt][ntd]);
        }
    }

    // ---- row-sum reduce -> rsum (recip) in LDS + rs in global ----
#pragma unroll
    for (int nt = 0; nt < 4; ++nt) {
        float v = lsum[nt];
        v += __shfl_xor(v, 16);
        v += __shfl_xor(v, 32);
        if (l < 16) red[w][nt * 16 + l] = v;
    }
    __syncthreads();  // red ready; also: all staging reads of buf complete
    if (tid < 64) {
        float nr = 1.0f / (red[0][tid] + red[1][tid] + red[2][tid] + red[3][tid]);
        rsum[tid] = nr;
        rs[(size_t)q * 64 + tid] = nr;
    }
    // ---- pr cross-wave reduce in buf (32 KB = 2 halves of 4096 floats) ----
    float* prbuf = reinterpret_cast<float*>(&buf[0][0]);
    if (w < 2) {
        float* dst = prbuf + w * 4096;
#pragma unroll
        for (int nt = 0; nt < 4; ++nt)
#pragma unroll
            for (int ntd = 0; ntd < 4; ++ntd)
#pragma unroll
                for (int r = 0; r < 4; ++r)
                    dst[(nt * 16 + lg * 4 + r) * 64 + ntd * 16 + lm] = pr[nt][ntd][r];
    }
    __syncthreads();  // halves written (w0,w1); rsum ready
    if (w >= 2) {
        float* dst = prbuf + (w - 2) * 4096;
#pragma unroll
        for (int nt = 0; nt < 4; ++nt)
#pragma unroll
            for (int ntd = 0; ntd < 4; ++ntd)
#pragma unroll
                for (int r = 0; r < 4; ++r)
                    dst[(nt * 16 + lg * 4 + r) * 64 + ntd * 16 + lm] += pr[nt][ntd][r];
    }
    __syncthreads();
    // ---- final: out[bh][q][d] = (half0 + half1) * rsum[bh] ----
#pragma unroll
    for (int i = 0; i < 4; ++i) {
        const int f4i = tid + i * 256;  // 0..1023 float4s
        float4 a = reinterpret_cast<const float4*>(prbuf)[f4i];
        float4 b = reinterpret_cast<const float4*>(prbuf)[1024 + f4i];
        const int fl = f4i * 4;
        const int bh = fl >> 6, d = fl & 63;
        const float nr = rsum[bh];
        float4 o = {(a.x + b.x) * nr, (a.y + b.y) * nr,
                    (a.z + b.z) * nr, (a.w + b.w) * nr};
        *reinterpret_cast<float4*>(&out[((size_t)bh * SQ + q) * DH + d]) = o;
    }
}

// ---------------- K3: Pn = e*recip written in place (final p_attn);
// out += Pn @ V. 1-D grid: qt = bid>>6, bh = bid&63 (balanced residency).
__global__ __launch_bounds__(256) void k_pv(float* __restrict__ P,
                                            const float* __restrict__ V,
                                            const float* __restrict__ rs,
                                            float* __restrict__ out) {
    const int bid = blockIdx.x;
    const int qt = bid >> 6;
    const int bh = bid & 63;
    const int tid = threadIdx.x;
    const int w = tid >> 6, l = tid & 63;
    const int lm = l & 15, lg = l >> 4;
    const int q0 = qt * 64 + w * 16;

    const float wrecip = rs[(size_t)(q0 + lm) * 64 + bh];
    float orecip[4];
#pragma unroll
    for (int r = 0; r < 4; ++r)
        orecip[r] = rs[(size_t)(q0 + lg * 4 + r) * 64 + bh];

    f32x4 acc[4] = {{0.f,0.f,0.f,0.f},{0.f,0.f,0.f,0.f},{0.f,0.f,0.f,0.f},{0.f,0.f,0.f,0.f}};
    const int kend = q0 + 16;
    for (int k0 = 0; k0 < kend; k0 += 32) {
        float* arow = P + ((size_t)bh * SQ + q0 + lm) * SK + k0 + lg * 8;
        float4 x0 = *reinterpret_cast<const float4*>(arow);
        float4 x1 = *reinterpret_cast<const float4*>(arow + 4);
        float4 y0 = {x0.x * wrecip, x0.y * wrecip, x0.z * wrecip, x0.w * wrecip};
        float4 y1 = {x1.x * wrecip, x1.y * wrecip, x1.z * wrecip, x1.w * wrecip};
        *reinterpret_cast<float4*>(arow) = y0;       // final normalized p_attn
        *reinterpret_cast<float4*>(arow + 4) = y1;
        bf16x8 a = pack_bf8(x0, x1);                 // unnormalized e
#pragma unroll
        for (int nt = 0; nt < 4; ++nt) {
            const float* bcol = V + ((size_t)bh * SK + k0 + lg * 8) * DH + nt * 16 + lm;
            bf16x8 b = load_bf8_strided(bcol, DH);
            acc[nt] = MFMA(a, b, acc[nt]);
        }
    }
#pragma unroll
    for (int nt = 0; nt < 4; ++nt)
#pragma unroll
        for (int r = 0; r < 4; ++r)
            out[((size_t)bh * SQ + q0 + lg * 4 + r) * DH + nt * 16 + lm] +=
                acc[nt][r] * orecip[r];
}

extern "C" void kernel_launch(void* const* d_in, const int* in_sizes, int n_in,
                              void* d_out, int out_size, void* d_ws, size_t ws_size,
                              hipStream_t stream) {
    const float* query  = (const float*)d_in[0];
    const float* key    = (const float*)d_in[1];
    const float* value  = (const float*)d_in[2];
    const float* bigr_k = (const float*)d_in[3];
    const float* bigr_v = (const float*)d_in[4];
    float* out = (float*)d_out;                       // BH*SQ*DH
    float* P   = out + (size_t)BH * SQ * DH;          // BH*SQ*SK
    float* rs  = (float*)d_ws;                        // [SQ][BH] recip = 256 KB
    unsigned short* cb = (unsigned short*)(rs + (size_t)SQ * 64);  // 128 MB bf16
    const bool packed =
        ws_size >= (size_t)SQ * 64 * 4 + (size_t)BH * SQ * SK * 2;

    if (packed) {
        k_scores<true><<<dim3(1024), 256, 0, stream>>>(query, key, P, cb);
        k_rel_pv<true><<<dim3(SQ), 256, 0, stream>>>(query, bigr_k, bigr_v, P, cb, out, rs);
    } else {
        k_scores<false><<<dim3(1024), 256, 0, stream>>>(query, key, P, cb);
        k_rel_pv<false><<<dim3(SQ), 256, 0, stream>>>(query, bigr_k, bigr_v, P, cb, out, rs);
    }
    k_pv<<<dim3(1024), 256, 0, stream>>>(P, value, rs, out);
}

// Round 25
// 349.561 us; speedup vs baseline: 1.2050x; 1.1093x over previous
//
#include <hip/hip_runtime.h>
#include <hip/hip_bf16.h>

// Relative-position causal attention, B=4 H=16 Q=K=1024 D=64 (fp32 in/out).
// d_out = [output (BH*Q*D) | p_attn (BH*Q*K)] fp32.
// K1 k_scores<PACKED>: content scores -> bf16 cb (causal) + fp32 zero-fill of
//     above-diagonal P tiles (streams free under glld pipeline).
// K2 k_rel_pv<PACKED>: rel+exp; e stored as bf16 IN PLACE into cb (same-lane
//     load-before-store, wave-private stripes => race-free) + fused PR.
// K3 k_pv<PACKED>: reads bf16 e from cb (ushort8 = MFMA A-fragment directly),
//     writes final normalized p_attn to P (kend covers full diagonal tile),
//     out += Pn@V.  Fallback (!PACKED): exact R16 path.

#define BH 64
#define SQ 1024
#define SK 1024
#define DH 64
#define SCALE 0.125f

typedef __attribute__((ext_vector_type(4))) float f32x4;
typedef __attribute__((ext_vector_type(8))) unsigned short ushort8;
typedef __attribute__((ext_vector_type(4))) unsigned short us4;
typedef __attribute__((ext_vector_type(8))) __bf16 bf16x8;

static __device__ inline unsigned short f2bf(float x) {
    unsigned u = __float_as_uint(x);
    unsigned r = u + 0x7FFFu + ((u >> 16) & 1u);
    return (unsigned short)(r >> 16);
}
static __device__ inline float bf2f(unsigned short s) {
    return __uint_as_float(((unsigned)s) << 16);
}

struct Frag2 { bf16x8 h, l; };

// Load 8 fp32, scale, split into hi/lo bf16 fragments (hi+lo == scaled value).
static __device__ inline Frag2 load_split(const float* __restrict__ p, float scale) {
    float4 x0 = *reinterpret_cast<const float4*>(p);
    float4 x1 = *reinterpret_cast<const float4*>(p + 4);
    float v[8] = {x0.x, x0.y, x0.z, x0.w, x1.x, x1.y, x1.z, x1.w};
    ushort8 uh, ul;
#pragma unroll
    for (int j = 0; j < 8; ++j) {
        float s = v[j] * scale;
        unsigned short h = f2bf(s);
        float r = s - bf2f(h);
        uh[j] = h;
        ul[j] = f2bf(r);
    }
    Frag2 f;
    f.h = __builtin_bit_cast(bf16x8, uh);
    f.l = __builtin_bit_cast(bf16x8, ul);
    return f;
}

static __device__ inline bf16x8 pack_bf8(float4 x0, float4 x1) {
    float v[8] = {x0.x, x0.y, x0.z, x0.w, x1.x, x1.y, x1.z, x1.w};
    ushort8 u;
#pragma unroll
    for (int j = 0; j < 8; ++j) u[j] = f2bf(v[j]);
    return __builtin_bit_cast(bf16x8, u);
}

static __device__ inline bf16x8 load_bf8_strided(const float* __restrict__ p, int stride) {
    ushort8 u;
#pragma unroll
    for (int j = 0; j < 8; ++j) u[j] = f2bf(p[(size_t)j * stride]);
    return __builtin_bit_cast(bf16x8, u);
}

#define MFMA(a, b, c) __builtin_amdgcn_mfma_f32_16x16x32_bf16((a), (b), (c), 0, 0, 0)

// async global -> LDS, 16B per lane; lds dest is wave-uniform base + lane*16
#define GLLD(g, s)                                                              \
    __builtin_amdgcn_global_load_lds(                                           \
        (const __attribute__((address_space(1))) void*)(g),                     \
        (__attribute__((address_space(3))) void*)(s), 16, 0, 0)

// stage a 64x64 fp32 tile (rows at src0 + row*DH) into buf[b]; WAVE-PRIVATE:
// wave w stages rows [w*16, w*16+16) and later reads only those rows.
// source pre-swizzled (chunk ^= row&7) so linear LDS + swizzled reads match.
#define STAGE64(src0, b)                                                        \
    do {                                                                        \
        _Pragma("unroll")                                                       \
        for (int j_ = 0; j_ < 4; ++j_) {                                        \
            const int idx_ = w * 256 + j_ * 64 + l;                             \
            const int row_ = idx_ >> 4;                                         \
            const int g_ = (idx_ & 15) ^ (row_ & 7);                            \
            GLLD((src0) + (size_t)row_ * DH + g_ * 4,                           \
                 &buf[b][w * 256 + j_ * 64]);                                   \
        }                                                                       \
    } while (0)

#define WAITVN(n)                                                               \
    do {                                                                        \
        asm volatile("s_waitcnt vmcnt(" #n ")" ::: "memory");                   \
        __builtin_amdgcn_sched_barrier(0);                                      \
    } while (0)

// ---------------- K1: content scores Q@K^T * scale. PACKED: bf16 causal -> cb
// AND fp32 zero-fill of above-diagonal P tiles. !PACKED: R16 fp32 path.
// 1-D grid: qt = bid>>6 (high bits), bh = bid&63.
template <bool PACKED>
__global__ __launch_bounds__(256, 4) void k_scores(const float* __restrict__ qp,
                                                   const float* __restrict__ kp,
                                                   float* __restrict__ P,
                                                   unsigned short* __restrict__ cb) {
    __shared__ float4 buf[2][1024];
    const int bid = blockIdx.x;
    const int qt = bid >> 6;
    const int bh = bid & 63;
    const int tid = threadIdx.x;
    const int w = tid >> 6, l = tid & 63;
    const int lm = l & 15, lg = l >> 4;
    const int q0 = qt * 64;

    Frag2 qh0[4], qh1[4];  // pre-scaled by SCALE
#pragma unroll
    for (int nt = 0; nt < 4; ++nt) {
        const float* qrow = qp + ((size_t)bh * SQ + q0 + nt * 16 + lm) * DH + lg * 8;
        qh0[nt] = load_split(qrow, SCALE);
        qh1[nt] = load_split(qrow + 32, SCALE);
    }
    const float* kb = kp + (size_t)bh * SK * DH;
    const int nt_ = qt + 1;

    STAGE64(kb, 0);
#pragma unroll 1
    for (int t = 0; t < nt_; ++t) {
        if (t + 1 < nt_) {
            STAGE64(kb + (size_t)(t + 1) * 64 * DH, (t + 1) & 1);
            WAITVN(4);  // stage(t)+stores(t-1) landed; stage(t+1) in flight
        } else {
            WAITVN(0);
        }
        const float4* L = buf[t & 1];
        const int R = w * 16 + lm;
        const int sw = R & 7;
        float4 f0 = L[R * 16 + ((2 * lg) ^ sw)];
        float4 f1 = L[R * 16 + ((2 * lg + 1) ^ sw)];
        float4 f2 = L[R * 16 + ((8 + 2 * lg) ^ sw)];
        float4 f3 = L[R * 16 + ((9 + 2 * lg) ^ sw)];
        bf16x8 alo = pack_bf8(f0, f1);
        bf16x8 ahi = pack_bf8(f2, f3);
        const int kq = t * 64 + w * 16 + lg * 4;
        const bool diag = (t == qt);
#pragma unroll
        for (int nt = 0; nt < 4; ++nt) {
            f32x4 acc = {0.f, 0.f, 0.f, 0.f};
            acc = MFMA(alo, qh0[nt].h, acc);
            acc = MFMA(alo, qh0[nt].l, acc);
            acc = MFMA(ahi, qh1[nt].h, acc);
            acc = MFMA(ahi, qh1[nt].l, acc);
            const int qe = q0 + nt * 16 + lm;
            if (PACKED) {
                us4 o;
#pragma unroll
                for (int r = 0; r < 4; ++r)
                    o[r] = f2bf((!diag || (kq + r <= qe)) ? acc[r] : 0.f);
                *reinterpret_cast<us4*>(&cb[((size_t)bh * SQ + qe) * SK + kq]) = o;
            } else {
                float ov[4];
#pragma unroll
                for (int r = 0; r < 4; ++r)
                    ov[r] = (!diag || (kq + r <= qe)) ? acc[r] : 0.f;
                float4 o;
                o.x = ov[0]; o.y = ov[1]; o.z = ov[2]; o.w = ov[3];
                *reinterpret_cast<float4*>(&P[((size_t)bh * SQ + qe) * SK + kq]) = o;
            }
        }
    }
    // zero-fill P tiles fully above the diagonal (both paths: final p_attn zeros)
    const float4 z = {0.f, 0.f, 0.f, 0.f};
#pragma unroll 1
    for (int t = nt_; t < 16; ++t) {
        const int kq = t * 64 + w * 16 + lg * 4;
#pragma unroll
        for (int nt = 0; nt < 4; ++nt) {
            const int qe = q0 + nt * 16 + lm;
            *reinterpret_cast<float4*>(&P[((size_t)bh * SQ + qe) * SK + kq]) = z;
        }
    }
}

// ---------------- K2: rel+exp + fused PR: out = (Σ e·bigr_v)/rowsum.
// 4-stripe balanced q map. PACKED: content read from cb, e written bf16 IN
// PLACE to cb (same-lane load-before-store, wave-private stripes). !PACKED: R16.
template <bool PACKED>
__global__ __launch_bounds__(256) void k_rel_pv(const float* __restrict__ query,
                                                const float* __restrict__ bigr_k,
                                                const float* __restrict__ bigr_v,
                                                float* __restrict__ P,
                                                unsigned short* __restrict__ cb,
                                                float* __restrict__ out,
                                                float* __restrict__ rs) {
    __shared__ float4 buf[2][1024];  // staging; reused for pr cross-wave reduce
    __shared__ float red[4][64];
    __shared__ float rsum[64];
    int q;
    {
        const int bid = blockIdx.x, c = bid & 255;
        switch (bid >> 8) {
            case 0:  q = 1023 - c; break;
            case 1:  q = c;        break;
            case 2:  q = 767 - c;  break;
            default: q = 256 + c;  break;
        }
    }
    const int KE = q + 1;
    const int nt_ = (KE + 63) >> 6;
    const int tid = threadIdx.x;
    const int w = tid >> 6, l = tid & 63;
    const int lm = l & 15, lg = l >> 4;

    Frag2 qh0[4], qh1[4];  // pre-scaled
    float* prow[4];
    unsigned short* crow[4];
#pragma unroll
    for (int nt = 0; nt < 4; ++nt) {
        const int bh = nt * 16 + lm;
        const float* qrow = query + ((size_t)bh * SQ + q) * DH + lg * 8;
        qh0[nt] = load_split(qrow, SCALE);
        qh1[nt] = load_split(qrow + 32, SCALE);
        prow[nt] = P + ((size_t)bh * SQ + q) * SK;
        crow[nt] = cb + ((size_t)bh * SQ + q) * SK;
    }
    const float* bk = bigr_k + (size_t)q * SK * DH;
    const float* bv = bigr_v + (size_t)q * SK * DH;
    float lsum[4] = {0.f, 0.f, 0.f, 0.f};
    f32x4 pr[4][4];  // [nt(bh group)][ntd(d group)]
#pragma unroll
    for (int a = 0; a < 4; ++a)
#pragma unroll
        for (int b = 0; b < 4; ++b) pr[a][b] = (f32x4){0.f, 0.f, 0.f, 0.f};

    STAGE64(bk, 0);
#pragma unroll 1
    for (int t = 0; t < nt_; ++t) {
        const int kq = t * 64 + w * 16 + lg * 4;
        us4 pcp[4];
        float4 pcf[4];
#pragma unroll
        for (int nt = 0; nt < 4; ++nt) {
            if (PACKED)
                pcp[nt] = *reinterpret_cast<const us4*>(crow[nt] + kq);
            else
                pcf[nt] = *reinterpret_cast<const float4*>(prow[nt] + kq);
        }
        // bigr_v B-fragments for this wave's 16-k stripe (consumed this iter)
        bf16x8 bvf[4];
        {
            const int kbw = t * 64 + w * 16 + 4 * lg;
#pragma unroll
            for (int ntd = 0; ntd < 4; ++ntd) {
                ushort8 u;
#pragma unroll
                for (int j = 0; j < 4; ++j)
                    u[j] = f2bf(bv[(size_t)(kbw + j) * DH + ntd * 16 + lm]);
                u[4] = 0; u[5] = 0; u[6] = 0; u[7] = 0;
                bvf[ntd] = __builtin_bit_cast(bf16x8, u);
            }
        }
        if (t + 1 < nt_) {
            STAGE64(bk + (size_t)(t + 1) * 64 * DH, (t + 1) & 1);
            WAITVN(4);  // stage(t)+pc+bv landed; stage(t+1) in flight
        } else {
            WAITVN(0);
        }
        const float4* L = buf[t & 1];
        const int R = w * 16 + lm;
        const int sw = R & 7;
        float4 f0 = L[R * 16 + ((2 * lg) ^ sw)];
        float4 f1 = L[R * 16 + ((2 * lg + 1) ^ sw)];
        float4 f2 = L[R * 16 + ((8 + 2 * lg) ^ sw)];
        float4 f3 = L[R * 16 + ((9 + 2 * lg) ^ sw)];
        bf16x8 alo = pack_bf8(f0, f1);
        bf16x8 ahi = pack_bf8(f2, f3);
#pragma unroll
        for (int nt = 0; nt < 4; ++nt) {
            f32x4 acc = {0.f, 0.f, 0.f, 0.f};
            acc = MFMA(alo, qh0[nt].h, acc);
            acc = MFMA(alo, qh0[nt].l, acc);
            acc = MFMA(ahi, qh1[nt].h, acc);
            acc = MFMA(ahi, qh1[nt].l, acc);
            float ov[4];
#pragma unroll
            for (int r = 0; r < 4; ++r) {
                const float c = PACKED ? bf2f(pcp[nt][r])
                                       : ((const float*)&pcf[nt])[r];
                float e = (kq + r < KE) ? __expf(c + acc[r]) : 0.f;
                ov[r] = e;
                lsum[nt] += e;
            }
            // e fragment (bf16, upper half zero) for PR; also the stored value
            ushort8 ua;
#pragma unroll
            for (int j = 0; j < 4; ++j) ua[j] = f2bf(ov[j]);
            ua[4] = 0; ua[5] = 0; ua[6] = 0; ua[7] = 0;
            if (PACKED) {
                us4 st = {ua[0], ua[1], ua[2], ua[3]};
                *reinterpret_cast<us4*>(crow[nt] + kq) = st;  // e in place
            } else {
                float4 o;
                o.x = ov[0]; o.y = ov[1]; o.z = ov[2]; o.w = ov[3];
                *reinterpret_cast<float4*>(prow[nt] + kq) = o;
            }
            bf16x8 af = __builtin_bit_cast(bf16x8, ua);
#pragma unroll
            for (int ntd = 0; ntd < 4; ++ntd)
                pr[nt][ntd] = MFMA(af, bvf[ntd], pr[nt][ntd]);
        }
    }

    // ---- row-sum reduce -> rsum (recip) in LDS + rs in global ----
#pragma unroll
    for (int nt = 0; nt < 4; ++nt) {
        float v = lsum[nt];
        v += __shfl_xor(v, 16);
        v += __shfl_xor(v, 32);
        if (l < 16) red[w][nt * 16 + l] = v;
    }
    __syncthreads();  // red ready; also: all staging reads of buf complete
    if (tid < 64) {
        float nr = 1.0f / (red[0][tid] + red[1][tid] + red[2][tid] + red[3][tid]);
        rsum[tid] = nr;
        rs[(size_t)q * 64 + tid] = nr;
    }
    // ---- pr cross-wave reduce in buf (32 KB = 2 halves of 4096 floats) ----
    float* prbuf = reinterpret_cast<float*>(&buf[0][0]);
    if (w < 2) {
        float* dst = prbuf + w * 4096;
#pragma unroll
        for (int nt = 0; nt < 4; ++nt)
#pragma unroll
            for (int ntd = 0; ntd < 4; ++ntd)
#pragma unroll
                for (int r = 0; r < 4; ++r)
                    dst[(nt * 16 + lg * 4 + r) * 64 + ntd * 16 + lm] = pr[nt][ntd][r];
    }
    __syncthreads();  // halves written (w0,w1); rsum ready
    if (w >= 2) {
        float* dst = prbuf + (w - 2) * 4096;
#pragma unroll
        for (int nt = 0; nt < 4; ++nt)
#pragma unroll
            for (int ntd = 0; ntd < 4; ++ntd)
#pragma unroll
                for (int r = 0; r < 4; ++r)
                    dst[(nt * 16 + lg * 4 + r) * 64 + ntd * 16 + lm] += pr[nt][ntd][r];
    }
    __syncthreads();
    // ---- final: out[bh][q][d] = (half0 + half1) * rsum[bh] ----
#pragma unroll
    for (int i = 0; i < 4; ++i) {
        const int f4i = tid + i * 256;  // 0..1023 float4s
        float4 a = reinterpret_cast<const float4*>(prbuf)[f4i];
        float4 b = reinterpret_cast<const float4*>(prbuf)[1024 + f4i];
        const int fl = f4i * 4;
        const int bh = fl >> 6, d = fl & 63;
        const float nr = rsum[bh];
        float4 o = {(a.x + b.x) * nr, (a.y + b.y) * nr,
                    (a.z + b.z) * nr, (a.w + b.w) * nr};
        *reinterpret_cast<float4*>(&out[((size_t)bh * SQ + q) * DH + d]) = o;
    }
}

// ---------------- K3: PACKED: read bf16 e from cb (A-fragment directly),
// write final normalized p_attn to P (kend = full diagonal-tile coverage),
// out += Pn@V. !PACKED: R16 in-place fp32 path.
template <bool PACKED>
__global__ __launch_bounds__(256) void k_pv(float* __restrict__ P,
                                            const unsigned short* __restrict__ cb,
                                            const float* __restrict__ V,
                                            const float* __restrict__ rs,
                                            float* __restrict__ out) {
    const int bid = blockIdx.x;
    const int qt = bid >> 6;
    const int bh = bid & 63;
    const int tid = threadIdx.x;
    const int w = tid >> 6, l = tid & 63;
    const int lm = l & 15, lg = l >> 4;
    const int q0 = qt * 64 + w * 16;

    const float wrecip = rs[(size_t)(q0 + lm) * 64 + bh];
    float orecip[4];
#pragma unroll
    for (int r = 0; r < 4; ++r)
        orecip[r] = rs[(size_t)(q0 + lg * 4 + r) * 64 + bh];

    f32x4 acc[4] = {{0.f,0.f,0.f,0.f},{0.f,0.f,0.f,0.f},{0.f,0.f,0.f,0.f},{0.f,0.f,0.f,0.f}};
    // PACKED covers the whole diagonal tile (writes its above-diag zeros too);
    // !PACKED keeps R16's minimal range (zeros already in P from k_rel_pv).
    const int kend = PACKED ? (qt + 1) * 64 : (q0 + 16);
    for (int k0 = 0; k0 < kend; k0 += 32) {
        bf16x8 a;
        if (PACKED) {
            const unsigned short* crow =
                cb + ((size_t)bh * SQ + q0 + lm) * SK + k0 + lg * 8;
            ushort8 ue = *reinterpret_cast<const ushort8*>(crow);
            a = __builtin_bit_cast(bf16x8, ue);  // e already bf16
            float* arow = P + ((size_t)bh * SQ + q0 + lm) * SK + k0 + lg * 8;
            float4 y0 = {bf2f(ue[0]) * wrecip, bf2f(ue[1]) * wrecip,
                         bf2f(ue[2]) * wrecip, bf2f(ue[3]) * wrecip};
            float4 y1 = {bf2f(ue[4]) * wrecip, bf2f(ue[5]) * wrecip,
                         bf2f(ue[6]) * wrecip, bf2f(ue[7]) * wrecip};
            *reinterpret_cast<float4*>(arow) = y0;       // final p_attn
            *reinterpret_cast<float4*>(arow + 4) = y1;
        } else {
            float* arow = P + ((size_t)bh * SQ + q0 + lm) * SK + k0 + lg * 8;
            float4 x0 = *reinterpret_cast<const float4*>(arow);
            float4 x1 = *reinterpret_cast<const float4*>(arow + 4);
            float4 y0 = {x0.x * wrecip, x0.y * wrecip, x0.z * wrecip, x0.w * wrecip};
            float4 y1 = {x1.x * wrecip, x1.y * wrecip, x1.z * wrecip, x1.w * wrecip};
            *reinterpret_cast<float4*>(arow) = y0;       // final p_attn
            *reinterpret_cast<float4*>(arow + 4) = y1;
            a = pack_bf8(x0, x1);                        // unnormalized e
        }
#pragma unroll
        for (int nt = 0; nt < 4; ++nt) {
            const float* bcol = V + ((size_t)bh * SK + k0 + lg * 8) * DH + nt * 16 + lm;
            bf16x8 b = load_bf8_strided(bcol, DH);
            acc[nt] = MFMA(a, b, acc[nt]);
        }
    }
#pragma unroll
    for (int nt = 0; nt < 4; ++nt)
#pragma unroll
        for (int r = 0; r < 4; ++r)
            out[((size_t)bh * SQ + q0 + lg * 4 + r) * DH + nt * 16 + lm] +=
                acc[nt][r] * orecip[r];
}

extern "C" void kernel_launch(void* const* d_in, const int* in_sizes, int n_in,
                              void* d_out, int out_size, void* d_ws, size_t ws_size,
                              hipStream_t stream) {
    const float* query  = (const float*)d_in[0];
    const float* key    = (const float*)d_in[1];
    const float* value  = (const float*)d_in[2];
    const float* bigr_k = (const float*)d_in[3];
    const float* bigr_v = (const float*)d_in[4];
    float* out = (float*)d_out;                       // BH*SQ*DH
    float* P   = out + (size_t)BH * SQ * DH;          // BH*SQ*SK
    float* rs  = (float*)d_ws;                        // [SQ][BH] recip = 256 KB
    unsigned short* cb = (unsigned short*)(rs + (size_t)SQ * 64);  // 128 MB bf16
    const bool packed =
        ws_size >= (size_t)SQ * 64 * 4 + (size_t)BH * SQ * SK * 2;

    if (packed) {
        k_scores<true><<<dim3(1024), 256, 0, stream>>>(query, key, P, cb);
        k_rel_pv<true><<<dim3(SQ), 256, 0, stream>>>(query, bigr_k, bigr_v, P, cb, out, rs);
        k_pv<true><<<dim3(1024), 256, 0, stream>>>(P, cb, value, rs, out);
    } else {
        k_scores<false><<<dim3(1024), 256, 0, stream>>>(query, key, P, cb);
        k_rel_pv<false><<<dim3(SQ), 256, 0, stream>>>(query, bigr_k, bigr_v, P, cb, out, rs);
        k_pv<false><<<dim3(1024), 256, 0, stream>>>(P, cb, value, rs, out);
    }
}